// Round 6
// baseline (1243.050 us; speedup 1.0000x reference)
//
#include <hip/hip_runtime.h>
#include <math.h>

// Sinkhorn [B=32, N=1024, N=1024] fp32, TAU=1, 10 iters.
// v7: persistent kernel that FITS the 128-VGPR budget instead of fighting it.
// Grid = 256 blocks (1/CU) x 1024 threads (16 waves). Wave owns 8 rows.
// Per-thread: x[8][12] = 96 regs (cols quads 0..2); quad 3 in LDS (128 KiB,
// thread-private, no barriers); Bm/Bl merge buffers 32 KiB -> LDS = 160 KiB
// exactly -> 1 block/CU pinned; amdgpu_waves_per_eu(4,4) matches (16 waves/CU
// = 4/EU) so the allocator targets exactly 128 regs. Live set ~112: no spill.
// v4-v6 lesson: cg::grid.sync() (__ockl_grid_sync call) pinned VGPR at 128
// regardless of launch bounds -> 43 floats/thread scratch thrash (385 us,
// +160 MB scratch traffic). v7 removes cg AND the >128-reg requirement:
// inline device-scope atomic barrier (ockl pattern), plain graph-capturable
// launch, co-residency by construction (1 block/CU).

#define BATCH 32
#define N 1024
#define NBLOCKS 256
#define NTHREADS 1024
#define RCHUNKS 32
#define ROWS_PER_BLK 32
#define PCHUNKS RCHUNKS

// LDS: q3[32768 floats]=128KiB | Bm[4096]=16KiB | Bl[4096]=16KiB  (160 KiB)
// Lcs (1024 floats) aliases the start of Bm (dead between col phases).
#define LDS_BYTES 163840
// barrier counters live in ws after pm/pl, one per iteration, 64B apart
#define CTR_OFF ((size_t)2 * NBLOCKS * N * sizeof(float))

__device__ __forceinline__ void grid_barrier(unsigned* c, unsigned target) {
    __threadfence();                 // release: make this block's stores visible
    __syncthreads();
    if (threadIdx.x == 0) {
        __hip_atomic_fetch_add(c, 1u, __ATOMIC_ACQ_REL, __HIP_MEMORY_SCOPE_AGENT);
        unsigned v;
        do {
            __builtin_amdgcn_s_sleep(2);
            v = __hip_atomic_load(c, __ATOMIC_ACQUIRE, __HIP_MEMORY_SCOPE_AGENT);
        } while (v < target);
    }
    __syncthreads();
    __threadfence();                 // acquire: drop stale cached lines
}

__global__ __attribute__((amdgpu_flat_work_group_size(1024, 1024),
                          amdgpu_waves_per_eu(4, 4)))
void sinkhorn_persist(const float* __restrict__ s, float* __restrict__ out,
                      float* __restrict__ pm, float* __restrict__ pl,
                      unsigned* __restrict__ ctr)
{
    extern __shared__ float lds[];
    float4* q3  = (float4*)lds;            // [(w*8+r)*64 + l] quad-3 data
    float*  Bm  = lds + 32768;             // [(w*4+e)*64 + l]
    float*  Bl  = Bm + 4096;
    float*  Lcs = Bm;                      // alias: consumed before Bm reuse

    const int cu = blockIdx.x;
    const int b  = cu >> 3;                // batch
    const int rb = cu & 7;                 // row-block (128 rows) within batch
    const int w  = threadIdx.x >> 6;       // 0..15
    const int l  = threadIdx.x & 63;

    // lane owns cols col(q,e) = 256*q + 4*l + e  (q in 0..3, e in 0..3)
    const size_t rowbase = ((size_t)(b * N) + rb * 128 + w * 8) * N;

    // ---------- load s once: 8 rows x 4 float4 ----------
    float x[8][12];
#pragma unroll
    for (int r = 0; r < 8; ++r) {
        const float4* p = (const float4*)(s + rowbase + (size_t)r * N);
        float4 v0 = p[l];
        float4 v1 = p[64 + l];
        float4 v2 = p[128 + l];
        float4 v3 = p[192 + l];
        x[r][0] = v0.x; x[r][1] = v0.y; x[r][2]  = v0.z; x[r][3]  = v0.w;
        x[r][4] = v1.x; x[r][5] = v1.y; x[r][6]  = v1.z; x[r][7]  = v1.w;
        x[r][8] = v2.x; x[r][9] = v2.y; x[r][10] = v2.z; x[r][11] = v2.w;
        q3[(w*8 + r)*64 + l] = v3;
    }

    float Lc[16];
#pragma unroll
    for (int k = 0; k < 16; ++k) Lc[k] = 0.f;

#pragma unroll 1
    for (int it = 0; it < 5; ++it) {
        // ---------- row phase (CU-local): x -= Lc; x -= rowLSE(x) ----------
#pragma unroll
        for (int r = 0; r < 8; ++r) {
            float4 h = q3[(w*8 + r)*64 + l];
#pragma unroll
            for (int k = 0; k < 12; ++k) x[r][k] -= Lc[k];
            h.x -= Lc[12]; h.y -= Lc[13]; h.z -= Lc[14]; h.w -= Lc[15];
            float m = fmaxf(fmaxf(h.x, h.y), fmaxf(h.z, h.w));
#pragma unroll
            for (int k = 0; k < 12; ++k) m = fmaxf(m, x[r][k]);
#pragma unroll
            for (int off = 32; off > 0; off >>= 1) m = fmaxf(m, __shfl_xor(m, off, 64));
            float s0 = __expf(h.x - m) + __expf(h.y - m);
            float s1 = __expf(h.z - m) + __expf(h.w - m);
#pragma unroll
            for (int k = 0; k < 12; k += 2) {
                s0 += __expf(x[r][k]   - m);
                s1 += __expf(x[r][k+1] - m);
            }
            float sum = s0 + s1;
#pragma unroll
            for (int off = 32; off > 0; off >>= 1) sum += __shfl_xor(sum, off, 64);
            float Lr = m + __logf(sum);
#pragma unroll
            for (int k = 0; k < 12; ++k) x[r][k] -= Lr;
            h.x -= Lr; h.y -= Lr; h.z -= Lr; h.w -= Lr;
            q3[(w*8 + r)*64 + l] = h;
        }

        // ---------- col phase: per-wave partial over its 8 rows ----------
#pragma unroll
        for (int q = 0; q < 4; ++q) {
            float cm[4], cl[4];
            if (q < 3) {
#pragma unroll
                for (int e = 0; e < 4; ++e) {
                    const int k = q*4 + e;
                    float m = x[0][k];
#pragma unroll
                    for (int r = 1; r < 8; ++r) m = fmaxf(m, x[r][k]);
                    float acc = 0.f;
#pragma unroll
                    for (int r = 0; r < 8; ++r) acc += __expf(x[r][k] - m);
                    cm[e] = m; cl[e] = acc;
                }
            } else {
                float4 mm = make_float4(-3.0e38f, -3.0e38f, -3.0e38f, -3.0e38f);
#pragma unroll
                for (int r = 0; r < 8; ++r) {
                    float4 h = q3[(w*8 + r)*64 + l];
                    mm.x = fmaxf(mm.x, h.x); mm.y = fmaxf(mm.y, h.y);
                    mm.z = fmaxf(mm.z, h.z); mm.w = fmaxf(mm.w, h.w);
                }
                float4 aa = make_float4(0.f, 0.f, 0.f, 0.f);
#pragma unroll
                for (int r = 0; r < 8; ++r) {
                    float4 h = q3[(w*8 + r)*64 + l];
                    aa.x += __expf(h.x - mm.x); aa.y += __expf(h.y - mm.y);
                    aa.z += __expf(h.z - mm.z); aa.w += __expf(h.w - mm.w);
                }
                cm[0] = mm.x; cm[1] = mm.y; cm[2] = mm.z; cm[3] = mm.w;
                cl[0] = aa.x; cl[1] = aa.y; cl[2] = aa.z; cl[3] = aa.w;
            }
#pragma unroll
            for (int e = 0; e < 4; ++e) {
                Bm[(w*4 + e)*64 + l] = cm[e];
                Bl[(w*4 + e)*64 + l] = cl[e];
            }
            __syncthreads();
            if (threadIdx.x < 256) {
                const int e  = threadIdx.x >> 6;
                const int ll = threadIdx.x & 63;
                float M = Bm[e*64 + ll], L = Bl[e*64 + ll];
#pragma unroll
                for (int w2 = 1; w2 < 16; ++w2) {
                    float m2 = Bm[(w2*4 + e)*64 + ll];
                    float l2 = Bl[(w2*4 + e)*64 + ll];
                    float mn = fmaxf(M, m2);
                    L = L * __expf(M - mn) + l2 * __expf(m2 - mn);
                    M = mn;
                }
                // storage idx (q*4+e)*64+ll  <->  actual col 256q+4*ll+e
                pm[(size_t)cu * N + (q*4 + e)*64 + ll] = M;
                pl[(size_t)cu * N + (q*4 + e)*64 + ll] = L;
            }
            __syncthreads();
        }

        // ---------- inline grid barrier (counter per iteration) ----------
        grid_barrier(ctr + it * 16, NBLOCKS);

        // ---------- every block merges its batch's 8 partials locally ------
        {
            const int idx = threadIdx.x;           // 0..1023 storage idx
            float M = -3.0e38f, L = 0.f;
#pragma unroll
            for (int k2 = 0; k2 < 8; ++k2) {
                float m2 = pm[(size_t)(b*8 + k2) * N + idx];
                float l2 = pl[(size_t)(b*8 + k2) * N + idx];
                float mn = fmaxf(M, m2);
                L = L * __expf(M - mn) + l2 * __expf(m2 - mn);
                M = mn;
            }
            Lcs[idx] = M + __logf(L);
        }
        __syncthreads();
#pragma unroll
        for (int q = 0; q < 4; ++q)
#pragma unroll
            for (int e = 0; e < 4; ++e)
                Lc[q*4 + e] = Lcs[(q*4 + e)*64 + l];
        __syncthreads();   // Lcs aliases Bm: all reads done before next col phase
    }

    // ---------- final: out = exp(x - Lc) ----------
#pragma unroll
    for (int r = 0; r < 8; ++r) {
        float4* orow = (float4*)(out + rowbase + (size_t)r * N);
        float4 h = q3[(w*8 + r)*64 + l];
        float4 o;
        o.x = __expf(x[r][0] - Lc[0]);   o.y = __expf(x[r][1] - Lc[1]);
        o.z = __expf(x[r][2] - Lc[2]);   o.w = __expf(x[r][3] - Lc[3]);
        orow[l] = o;
        o.x = __expf(x[r][4] - Lc[4]);   o.y = __expf(x[r][5] - Lc[5]);
        o.z = __expf(x[r][6] - Lc[6]);   o.w = __expf(x[r][7] - Lc[7]);
        orow[64 + l] = o;
        o.x = __expf(x[r][8] - Lc[8]);   o.y = __expf(x[r][9] - Lc[9]);
        o.z = __expf(x[r][10] - Lc[10]); o.w = __expf(x[r][11] - Lc[11]);
        orow[128 + l] = o;
        o.x = __expf(h.x - Lc[12]); o.y = __expf(h.y - Lc[13]);
        o.z = __expf(h.z - Lc[14]); o.w = __expf(h.w - Lc[15]);
        orow[192 + l] = o;
    }
}

// ================= fallback: round-1 3-kernel path =================
__global__ __launch_bounds__(512, 4) void fused_pair_kernel(
    const float* __restrict__ s, const float* __restrict__ c,
    float* __restrict__ r, float* __restrict__ pm, float* __restrict__ pl,
    int has_c)
{
    const int bc    = blockIdx.x;
    const int b     = bc >> 5;
    const int chunk = bc & 31;
    const int row0  = chunk * ROWS_PER_BLK;
    const int wave  = threadIdx.x >> 6;
    const int lane  = threadIdx.x & 63;

    __shared__ float4 sm4[8][256];
    __shared__ float4 sl4[8][256];

    float4 cv[4];
    if (has_c) {
        const float4* c4 = (const float4*)(c + b * N);
#pragma unroll
        for (int k = 0; k < 4; k++) cv[k] = c4[lane + 64 * k];
    } else {
#pragma unroll
        for (int k = 0; k < 4; k++) cv[k] = make_float4(0.f, 0.f, 0.f, 0.f);
    }

    float x[4][16];
#pragma unroll
    for (int rp = 0; rp < 4; rp++) {
        const float4* srow =
            (const float4*)(s + ((size_t)(b * N + row0 + wave * 4 + rp)) * N);
#pragma unroll
        for (int k = 0; k < 4; k++) {
            float4 v = srow[lane + 64 * k];
            x[rp][4*k+0] = v.x + cv[k].x;
            x[rp][4*k+1] = v.y + cv[k].y;
            x[rp][4*k+2] = v.z + cv[k].z;
            x[rp][4*k+3] = v.w + cv[k].w;
        }
    }

    float rv[4];
#pragma unroll
    for (int rp = 0; rp < 4; rp++) {
        float m = x[rp][0];
#pragma unroll
        for (int t = 1; t < 16; t++) m = fmaxf(m, x[rp][t]);
#pragma unroll
        for (int off = 32; off > 0; off >>= 1) m = fmaxf(m, __shfl_xor(m, off, 64));
        float sum = 0.f;
#pragma unroll
        for (int t = 0; t < 16; t++) sum += __expf(x[rp][t] - m);
#pragma unroll
        for (int off = 32; off > 0; off >>= 1) sum += __shfl_xor(sum, off, 64);
        rv[rp] = -(m + __logf(sum));
        if (lane == 0) r[b * N + row0 + wave * 4 + rp] = rv[rp];
    }

#pragma unroll
    for (int k = 0; k < 4; k++) {
        float pmv[4], plv[4];
#pragma unroll
        for (int e = 0; e < 4; e++) {
            float x0 = x[0][4*k+e] + rv[0];
            float x1 = x[1][4*k+e] + rv[1];
            float x2 = x[2][4*k+e] + rv[2];
            float x3 = x[3][4*k+e] + rv[3];
            float m = fmaxf(fmaxf(x0, x1), fmaxf(x2, x3));
            plv[e] = __expf(x0 - m) + __expf(x1 - m) +
                     __expf(x2 - m) + __expf(x3 - m);
            pmv[e] = m;
        }
        sm4[wave][lane + 64 * k] = make_float4(pmv[0], pmv[1], pmv[2], pmv[3]);
        sl4[wave][lane + 64 * k] = make_float4(plv[0], plv[1], plv[2], plv[3]);
    }
    __syncthreads();

    const float* smf = (const float*)sm4;
    const float* slf = (const float*)sl4;
#pragma unroll
    for (int cc = 0; cc < 2; cc++) {
        const int col = threadIdx.x + cc * 512;
        float M = smf[col], L = slf[col];
#pragma unroll
        for (int w2 = 1; w2 < 8; w2++) {
            float m = smf[w2 * N + col], l2 = slf[w2 * N + col];
            float mn = fmaxf(M, m);
            L = L * __expf(M - mn) + l2 * __expf(m - mn);
            M = mn;
        }
        pm[(size_t)bc * N + col] = M;
        pl[(size_t)bc * N + col] = L;
    }
}

__global__ __launch_bounds__(1024) void col_combine_kernel(
    const float* __restrict__ pm, const float* __restrict__ pl,
    float* __restrict__ c)
{
    const int b  = blockIdx.x >> 2;
    const int q  = blockIdx.x & 3;
    const int jc = threadIdx.x & 255;
    const int kg = threadIdx.x >> 8;
    const int j  = q * 256 + jc;
    float M = -3.0e38f, L = 0.f;
#pragma unroll
    for (int k = 0; k < 8; k++) {
        const int kk = kg * 8 + k;
        float m = pm[((size_t)(b * PCHUNKS + kk)) * N + j];
        float l = pl[((size_t)(b * PCHUNKS + kk)) * N + j];
        float mn = fmaxf(M, m);
        L = L * __expf(M - mn) + l * __expf(m - mn); M = mn;
    }
    __shared__ float smm[4][256], sll[4][256];
    smm[kg][jc] = M; sll[kg][jc] = L;
    __syncthreads();
    if (kg == 0) {
#pragma unroll
        for (int g2 = 1; g2 < 4; g2++) {
            float m = smm[g2][jc], l = sll[g2][jc];
            float mn = fmaxf(M, m);
            L = L * __expf(M - mn) + l * __expf(m - mn); M = mn;
        }
        c[b * N + j] = -(M + __logf(L));
    }
}

__global__ __launch_bounds__(256) void zero_c_kernel(float* __restrict__ c) {
    c[blockIdx.x * 256 + threadIdx.x] = 0.0f;
}

__global__ __launch_bounds__(256) void row_lse_kernel(const float* __restrict__ s,
                                                      const float* __restrict__ c,
                                                      float* __restrict__ r) {
    const int wave = threadIdx.x >> 6;
    const int lane = threadIdx.x & 63;
    const int row  = blockIdx.x * 4 + wave;
    const int b    = row >> 10;
    const float4* srow = (const float4*)(s + (size_t)row * N);
    const float4* crow = (const float4*)(c + (size_t)b * N);
    float x[16];
#pragma unroll
    for (int k = 0; k < 4; k++) {
        float4 v = srow[lane + k * 64];
        float4 cv = crow[lane + k * 64];
        x[4*k+0]=v.x+cv.x; x[4*k+1]=v.y+cv.y; x[4*k+2]=v.z+cv.z; x[4*k+3]=v.w+cv.w;
    }
    float m = x[0];
#pragma unroll
    for (int t = 1; t < 16; t++) m = fmaxf(m, x[t]);
#pragma unroll
    for (int off = 32; off > 0; off >>= 1) m = fmaxf(m, __shfl_xor(m, off, 64));
    float sum = 0.f;
#pragma unroll
    for (int t = 0; t < 16; t++) sum += __expf(x[t] - m);
#pragma unroll
    for (int off = 32; off > 0; off >>= 1) sum += __shfl_xor(sum, off, 64);
    if (lane == 0) r[row] = -(m + __logf(sum));
}

__global__ __launch_bounds__(1024) void col_lse_direct_kernel(const float* __restrict__ s,
                                                              const float* __restrict__ r,
                                                              float* __restrict__ c) {
    const int b = blockIdx.x;
    const int j = threadIdx.x;
    const float* rb = r + b * N;
    const float* base = s + (size_t)b * N * N + j;
    float m = -3.0e38f, l = 0.f;
    for (int i = 0; i < N; i++) {
        float x  = base[(size_t)i * N] + rb[i];
        float mn = fmaxf(m, x);
        l = l * __expf(m - mn) + __expf(x - mn);
        m = mn;
    }
    c[b * N + j] = -(m + __logf(l));
}

__global__ __launch_bounds__(256) void finalize_kernel(const float* __restrict__ s,
                                                       const float* __restrict__ r,
                                                       const float* __restrict__ c,
                                                       float* __restrict__ out) {
    const int f4  = blockIdx.x * 256 + threadIdx.x;
    const int j4  = f4 & 255;
    const int row = f4 >> 8;
    const int b   = row >> 10;
    float4 v  = ((const float4*)s)[f4];
    float  rr = r[row];
    float4 cc = ((const float4*)c)[(b << 8) + j4];
    float4 o;
    o.x = __expf(v.x + rr + cc.x);
    o.y = __expf(v.y + rr + cc.y);
    o.z = __expf(v.z + rr + cc.z);
    o.w = __expf(v.w + rr + cc.w);
    ((float4*)out)[f4] = o;
}

extern "C" void kernel_launch(void* const* d_in, const int* in_sizes, int n_in,
                              void* d_out, int out_size, void* d_ws, size_t ws_size,
                              hipStream_t stream) {
    const float* s = (const float*)d_in[0];
    float* out = (float*)d_out;

    // ---- persistent path (plain launch + inline grid barrier) ----
    static int inited = 0, persist_ok = 0;
    if (!inited) {
        persist_ok = (hipFuncSetAttribute((const void*)sinkhorn_persist,
                        hipFuncAttributeMaxDynamicSharedMemorySize,
                        LDS_BYTES) == hipSuccess);
        inited = 1;
    }

    const size_t needed_persist = CTR_OFF + 5 * 64;
    if (persist_ok && ws_size >= needed_persist) {
        float* pmc = (float*)d_ws;                         // 256*N
        float* plc = pmc + NBLOCKS * N;                    // 256*N
        unsigned* ctr = (unsigned*)((char*)d_ws + CTR_OFF);
        hipError_t e0 = hipMemsetAsync(ctr, 0, 5 * 64, stream);
        if (e0 == hipSuccess) {
            sinkhorn_persist<<<NBLOCKS, NTHREADS, LDS_BYTES, stream>>>(
                s, out, pmc, plc, ctr);
            if (hipGetLastError() == hipSuccess) return;
        }
        persist_ok = 0;  // fall through to non-persistent path
    }

    // ---- fallback paths ----
    float* c  = (float*)d_ws;
    float* r  = c + BATCH * N;
    float* pm = r + BATCH * N;
    float* pl = pm + BATCH * PCHUNKS * N;

    const size_t needed =
        (size_t)(2 * BATCH * N + 2 * BATCH * PCHUNKS * N) * sizeof(float);

    if (ws_size >= needed) {
        for (int p = 0; p < 5; p++) {
            fused_pair_kernel<<<BATCH * RCHUNKS, 512, 0, stream>>>(
                s, c, r, pm, pl, p > 0 ? 1 : 0);
            col_combine_kernel<<<BATCH * 4, 1024, 0, stream>>>(pm, pl, c);
        }
    } else {
        zero_c_kernel<<<(BATCH * N) / 256, 256, 0, stream>>>(c);
        for (int it = 0; it < 10; it++) {
            if ((it & 1) == 0)
                row_lse_kernel<<<(BATCH * N) / 4, 256, 0, stream>>>(s, c, r);
            else
                col_lse_direct_kernel<<<BATCH, 1024, 0, stream>>>(s, r, c);
        }
    }

    const int total_f4 = BATCH * N * N / 4;
    finalize_kernel<<<total_f4 / 256, 256, 0, stream>>>(s, r, c, out);
}